// Round 4
// baseline (507.644 us; speedup 1.0000x reference)
//
#include <hip/hip_runtime.h>
#include <math.h>

#define D 256
#define TOPK 1024
#define EPS 1e-8f

typedef __attribute__((ext_vector_type(8))) short short8;
typedef __attribute__((ext_vector_type(4))) float f32x4;

__device__ __forceinline__ unsigned encf(float f){
  unsigned b = __float_as_uint(f);
  return b ^ ((unsigned)((int)b >> 31) | 0x80000000u);
}
__device__ __forceinline__ float decf(unsigned u){
  unsigned b = (u & 0x80000000u) ? (u ^ 0x80000000u) : ~u;
  return __uint_as_float(b);
}

__device__ __forceinline__ void gload16(const void* g, void* l){
  __builtin_amdgcn_global_load_lds(
      (const __attribute__((address_space(1))) unsigned*)g,
      (__attribute__((address_space(3))) unsigned*)l, 16, 0, 0);
}

// ---------------------------------------------------------------------------
// Wbs global layout (bf16x3 split of W_e, per col-quarter, lane-linear order):
//   quarter q (64 cols), stageblk = ch*3 + s (ch = k-chunk 0..7, s = split),
//   cf = colfrag 0..3, lane l = g*16 + c0 (g = k-slot group, c0 = col%16),
//   e = k elem 0..7:  short idx = q*49152 + (stageblk*4+cf)*512 + l*8 + e
// holds W[col = q*64+cf*16+c0][k = 32*ch + 8*g + e], split s.
// A wave's ds_read_b128 for (ch,s,cf) is then base + lane*16: conflict-free,
// and global->LDS staging is a pure linear copy (swizzle baked both sides).
// ---------------------------------------------------------------------------
__global__ __launch_bounds__(256) void k1_setup(
    const float* __restrict__ emb, const float* __restrict__ dtab,
    const float* __restrict__ W, const int* __restrict__ srcp,
    short* __restrict__ Wbs, float* __restrict__ WD, float* __restrict__ QN,
    unsigned* __restrict__ SC, unsigned* __restrict__ ZB, int N)
{
  int tid = threadIdx.x;
  int blk = blockIdx.x;
  if (blk == 0 && tid == 0){
    SC[0]=0u;                 // MAXE (encoded max logit)
    ((float*)SC)[1]=0.0f;     // SUME
    SC[2]=0u;                 // EQC
    SC[3]=0u;                 // PFX
    SC[4]=(unsigned)TOPK;     // KP (remaining quota)
  }
  if (blk < 256){
    int c = blk;              // output col (= W row)
    int k = tid;              // k index
    float f = W[(size_t)c*258 + k];
    unsigned u  = __float_as_uint(f);
    unsigned hb = u & 0xffff0000u;
    float r = f - __uint_as_float(hb);
    unsigned mb = __float_as_uint(r) & 0xffff0000u;
    float r2 = r - __uint_as_float(mb);
    unsigned lb = __float_as_uint(r2) & 0xffff0000u;
    int q = c >> 6, colq = c & 63, cf = colq >> 4, c0 = colq & 15;
    int ch = k >> 5, kk = k & 31, g = kk >> 3, e = kk & 7;
    size_t idx0 = (size_t)q*49152 + ((size_t)(ch*3)*4 + cf)*512 + (g*16 + c0)*8 + e;
    Wbs[idx0       ] = (short)(hb>>16);
    Wbs[idx0 + 2048] = (short)(mb>>16);   // s=1: +4*512
    Wbs[idx0 + 4096] = (short)(lb>>16);   // s=2
  } else if (blk == 256){
    int k = tid;
    float w6 = W[(size_t)k*258 + 256], w7 = W[(size_t)k*258 + 257];
    WD[k]     = w6*dtab[0] + w7*dtab[1];
    WD[256+k] = w6*dtab[2] + w7*dtab[3];
    WD[512+k] = w6*dtab[4] + w7*dtab[5];
    int src = srcp[0];
    float qk = emb[(size_t)src*D + k];
    __shared__ float red[256];
    red[tid]=qk*qk; __syncthreads();
    for (int s2=128;s2>0;s2>>=1){ if (tid<s2) red[tid]+=red[tid+s2]; __syncthreads(); }
    if (tid==0) QN[0] = sqrtf(red[0]);
  } else {
    // zero H0,H1,H2 (6144 u32) + Sg (N f32) + Qg (N f32), contiguous at ZB
    unsigned zid = (unsigned)(blk-257)*256u + (unsigned)tid;
    if (zid < 6144u + 2u*(unsigned)N) ZB[zid] = 0u;
  }
}

// ---------------------------------------------------------------------------
// K2: bf16x3 MFMA GEMM, B resident in LDS (one 64-col quarter, 96KB, staged
// ONCE), A streamed from L3. Grid = 4 quarters x 64 row-blocks (1 block/CU).
// 8 waves x 64 rows/wave/iter = 512 rows/iter, ~7 iters of the block's 3125
// rows. NO barriers / staging in the main loop. Per wave per chunk: 12
// conflict-free lane-linear ds_read_b128 feed 96 MFMAs (8:1). Epilogue
// reduces S=sum(v*q), Q=sum(v^2) over the quarter's 64 cols (shfl over 16
// lanes) and atomicAdds per-row partials into Sg/Qg.
// ---------------------------------------------------------------------------
#define SPLIT(x0,x1, AH,AM,AL) do{ float xs[8]={x0.x,x0.y,x0.z,x0.w,x1.x,x1.y,x1.z,x1.w}; \
  _Pragma("unroll") for(int _e=0;_e<8;++_e){ float _f=xs[_e]; unsigned _u=__float_as_uint(_f); \
    unsigned _hb=_u&0xffff0000u; float _r=_f-__uint_as_float(_hb); \
    unsigned _mb=__float_as_uint(_r)&0xffff0000u; float _r2=_r-__uint_as_float(_mb); \
    unsigned _lb=__float_as_uint(_r2)&0xffff0000u; \
    AH[_e]=(short)(_hb>>16); AM[_e]=(short)(_mb>>16); AL[_e]=(short)(_lb>>16);} }while(0)

#define READB(S_) do{ _Pragma("unroll") for (int _cf=0;_cf<4;++_cf) \
  b[_cf] = *(const short8*)(Bsh + ((ch*3+(S_))*4+_cf)*512 + (lane<<3)); }while(0)

#define MFMA_PASS(ASPL) do{ _Pragma("unroll") for (int _rf=0;_rf<4;++_rf){ \
  _Pragma("unroll") for (int _cf=0;_cf<4;++_cf) \
    acc[_rf][_cf] = __builtin_amdgcn_mfma_f32_16x16x32_bf16(ASPL[_rf], b[_cf], acc[_rf][_cf],0,0,0); } }while(0)

__global__ __launch_bounds__(512,2) void k2_main(
    const float* __restrict__ emb, const int* __restrict__ dist,
    const int* __restrict__ srcp, const short* __restrict__ Wbs,
    const float* __restrict__ WD, float* __restrict__ Sg,
    float* __restrict__ Qg, int N)
{
  extern __shared__ short Bsh[];   // 49152 shorts = 96KB
  int tid = threadIdx.x;
  int wave = tid >> 6;
  int lane = tid & 63;
  int g = lane >> 4;
  int c0 = lane & 15;

  int q  = blockIdx.x & 3;         // col quarter
  int rb = blockIdx.x >> 2;        // row block 0..63
  int RPB = (N + 63) >> 6;
  int rstart = rb * RPB;
  int rend = rstart + RPB; if (rend > N) rend = N;
  int ITERS = (RPB + 511) >> 9;

  // ---- stage B quarter into LDS (once), pure linear copy ----
  const char* Wq = (const char*)(Wbs + (size_t)q*49152);
  #pragma unroll
  for (int i=0;i<12;++i){
    int off = (i*512 + tid)*16;
    gload16(Wq + off, (char*)Bsh + off);
  }

  // ---- per-lane epilogue tables (cols of this quarter) ----
  int colbase = q*64;
  float qq[4], wdq0[4], wdq1[4], wdq2[4];
  {
    int src = srcp[0];
    #pragma unroll
    for (int cf=0;cf<4;++cf){
      int col = colbase + cf*16 + c0;
      qq[cf]   = emb[(size_t)src*D + col];
      wdq0[cf] = WD[col];
      wdq1[cf] = WD[256+col];
      wdq2[cf] = WD[512+col];
    }
  }
  __syncthreads();   // B resident; no further barriers

  for (int it=0; it<ITERS; ++it){
    int rowbase = rstart + it*512 + wave*64;
    const float* xp0; const float* xp1; const float* xp2; const float* xp3;
    {
      int r0 = rowbase + c0;        xp0 = emb + (size_t)(r0<N? r0 : N-1)*D + 8*g;
      int r1 = rowbase + 16 + c0;   xp1 = emb + (size_t)(r1<N? r1 : N-1)*D + 8*g;
      int r2 = rowbase + 32 + c0;   xp2 = emb + (size_t)(r2<N? r2 : N-1)*D + 8*g;
      int r3 = rowbase + 48 + c0;   xp3 = emb + (size_t)(r3<N? r3 : N-1)*D + 8*g;
    }
    f32x4 acc[4][4];
    #pragma unroll
    for (int rf=0;rf<4;++rf)
      #pragma unroll
      for (int cf=0;cf<4;++cf) acc[rf][cf] = (f32x4){0.f,0.f,0.f,0.f};

    float4 xc[4][2], xn[4][2];
    xc[0][0]=*(const float4*)(xp0); xc[0][1]=*(const float4*)(xp0+4);
    xc[1][0]=*(const float4*)(xp1); xc[1][1]=*(const float4*)(xp1+4);
    xc[2][0]=*(const float4*)(xp2); xc[2][1]=*(const float4*)(xp2+4);
    xc[3][0]=*(const float4*)(xp3); xc[3][1]=*(const float4*)(xp3+4);

    for (int ch=0; ch<8; ++ch){
      if (ch < 7){
        int o = 32*(ch+1);
        xn[0][0]=*(const float4*)(xp0+o); xn[0][1]=*(const float4*)(xp0+o+4);
        xn[1][0]=*(const float4*)(xp1+o); xn[1][1]=*(const float4*)(xp1+o+4);
        xn[2][0]=*(const float4*)(xp2+o); xn[2][1]=*(const float4*)(xp2+o+4);
        xn[3][0]=*(const float4*)(xp3+o); xn[3][1]=*(const float4*)(xp3+o+4);
      }
      short8 ah[4], am[4], al[4];
      #pragma unroll
      for (int rf=0;rf<4;++rf) SPLIT(xc[rf][0], xc[rf][1], ah[rf], am[rf], al[rf]);

      short8 b[4];
      READB(0);                 // Bh
      MFMA_PASS(ah);            // hh
      MFMA_PASS(am);            // mh
      MFMA_PASS(al);            // lh
      READB(1);                 // Bm
      MFMA_PASS(ah);            // hm
      MFMA_PASS(am);            // mm
      READB(2);                 // Bl
      MFMA_PASS(ah);            // hl

      if (ch < 7){
        #pragma unroll
        for (int rf=0;rf<4;++rf){ xc[rf][0]=xn[rf][0]; xc[rf][1]=xn[rf][1]; }
      }
    }

    // ---- epilogue: S,Q partials over this quarter's 64 cols ----
    #pragma unroll
    for (int rf=0; rf<4; ++rf){
      #pragma unroll
      for (int r=0;r<4;++r){
        int row = rowbase + rf*16 + 4*g + r;
        bool wr = (row < rend);
        int dv = wr ? dist[row] : 3;
        int di = dv-1; di = di<0?0:(di>2?2:di);
        float S=0.f, Q=0.f;
        #pragma unroll
        for (int cf=0;cf<4;++cf){
          float wd = (di==0)? wdq0[cf] : (di==1)? wdq1[cf] : wdq2[cf];
          float v = acc[rf][cf][r] + wd;
          S = fmaf(v, qq[cf], S);
          Q = fmaf(v, v, Q);
        }
        #pragma unroll
        for (int off=1; off<16; off<<=1){
          S += __shfl_xor(S, off);
          Q += __shfl_xor(Q, off);
        }
        if (c0==0 && wr){
          atomicAdd(&Sg[row], S);
          atomicAdd(&Qg[row], Q);
        }
      }
    }
  }
}

// ---------------------------------------------------------------------------
// K2b: combine quarter partials -> cos/weight/encode, pass-0 histogram,
// global max logit.
// ---------------------------------------------------------------------------
__global__ __launch_bounds__(256) void k2b_enc(
    const int* __restrict__ dist, const float* __restrict__ Sg,
    const float* __restrict__ Qg, const float* __restrict__ QN,
    unsigned* __restrict__ UK, unsigned* __restrict__ SC,
    unsigned* __restrict__ H0, int N)
{
  __shared__ unsigned h[2048];
  int tid = threadIdx.x;
  int lane = tid & 63;
  for (int i=tid;i<2048;i+=256) h[i]=0u;
  __syncthreads();
  int n = blockIdx.x*256 + tid;
  float sval = -INFINITY;
  if (n < N){
    float S = Sg[n], Q = Qg[n];
    int dv = dist[n];
    float qn = QN[0];
    float den = fmaxf(sqrtf(Q), EPS) * fmaxf(qn, EPS);
    float cosv = S/den;
    float wgt = (dv==1)?1.5f:((dv==2)?2.0f:1.0f);
    float wv = (dv<=2)? cosv*wgt : -INFINITY;
    unsigned u = encf(wv);
    UK[n] = u;
    if (u > 0x007FFFFFu) atomicAdd(&h[u>>21],1u);
    sval = S;
  }
  float m = sval;
  #pragma unroll
  for (int off=32;off>0;off>>=1) m = fmaxf(m, __shfl_down(m, off));
  if (lane==0) atomicMax(&SC[0], encf(m));
  __syncthreads();
  for (int i=tid;i<2048;i+=256){ unsigned v=h[i]; if (v) atomicAdd(&H0[i], v); }
}

// ---------------------------------------------------------------------------
// Radix-select histogram passes 1,2 (LDS-privatized).  (unchanged)
// ---------------------------------------------------------------------------
__global__ __launch_bounds__(256) void kh_hist(
    const unsigned* __restrict__ UK, const unsigned* __restrict__ SC,
    unsigned* __restrict__ Hp, int pass, int N)
{
  __shared__ unsigned h[2048];
  int bins = (pass==2)?1024:2048;
  int tid = threadIdx.x;
  for (int i=tid;i<bins;i+=256) h[i]=0u;
  __syncthreads();
  unsigned pfx = SC[3];
  int n = blockIdx.x*256 + tid;
  if (n < N){
    unsigned u = UK[n];
    bool incl; unsigned bin;
    if (pass==1){ incl = ((u>>21)==pfx); bin = (u>>10)&2047u; }
    else { incl = ((u>>10)==pfx); bin = u & 1023u; }
    if (incl) atomicAdd(&h[bin], 1u);
  }
  __syncthreads();
  for (int i=tid;i<bins;i+=256){ unsigned v=h[i]; if (v) atomicAdd(&Hp[i], v); }
}

__global__ __launch_bounds__(256) void ks_scan(
    const unsigned* __restrict__ Hp, unsigned* __restrict__ SC, int pass)
{
  __shared__ unsigned h[2048];
  __shared__ unsigned part[256];
  int bins=(pass==2)?1024:2048;
  int per = bins/256;
  int tid=threadIdx.x;
  unsigned ps=0;
  for (int i=0;i<per;++i){ unsigned v=Hp[tid*per+i]; h[tid*per+i]=v; ps+=v; }
  part[tid]=ps;
  __syncthreads();
  if (tid==0){
    unsigned Kp = SC[4];
    unsigned cum=0;
    int sc2=0;
    for (int t=255;t>=0;--t){
      if (cum + part[t] >= Kp){ sc2=t; break; }
      cum += part[t];
    }
    int sel = sc2*per;
    for (int b2=sc2*per+per-1; b2>=sc2*per; --b2){
      if (cum + h[b2] >= Kp){ sel=b2; break; }
      cum += h[b2];
    }
    SC[4] = Kp - cum;                         // remaining quota among == bin
    int bitsp = (pass==2)?10:11;
    SC[3] = (SC[3] << bitsp) | (unsigned)sel; // extend prefix
  }
}

// ---------------------------------------------------------------------------
// K6: write mask (topk-strict | dist==1 | src), collect ==T list, sum-exp.
// ---------------------------------------------------------------------------
__global__ __launch_bounds__(256) void k6_final(
    const int* __restrict__ dist, const int* __restrict__ srcp,
    const float* __restrict__ Sv, const unsigned* __restrict__ UK,
    unsigned* __restrict__ SC, unsigned* __restrict__ EQL,
    float* __restrict__ out, int N)
{
  int tid=threadIdx.x;
  int n=blockIdx.x*256+tid;
  unsigned T = SC[3];
  float M = decf(SC[0]);
  int src = srcp[0];
  float e=0.f;
  if (n<N){
    unsigned u = UK[n];
    int dv = dist[n];
    bool base = (u>T) || (dv==1) || (n==src);
    out[1+n] = base ? 1.0f : 0.0f;
    if (u==T){
      unsigned i = atomicAdd(&SC[2], 1u);
      if (i < 4096u) EQL[i] = (unsigned)n;
    }
    e = expf(Sv[n]-M);
  }
  __shared__ float red[256];
  red[tid]=e; __syncthreads();
  for (int st=128;st>0;st>>=1){ if (tid<st) red[tid]+=red[tid+st]; __syncthreads(); }
  if (tid==0) atomicAdd((float*)&SC[1], red[0]);
}

// ---------------------------------------------------------------------------
// K7: loss = L*lse - sum(logits[labels]); resolve ==T ties lowest-index-first.
// ---------------------------------------------------------------------------
__global__ __launch_bounds__(256) void k7_loss(
    const int* __restrict__ labels, const float* __restrict__ Sv,
    unsigned* __restrict__ SC, const unsigned* __restrict__ EQL,
    float* __restrict__ out, int L)
{
  __shared__ float red[256];
  __shared__ unsigned lst[4096];
  int tid=threadIdx.x;
  float v=0.f;
  if (tid<L) v = Sv[labels[tid]];
  red[tid]=v; __syncthreads();
  for (int st=128;st>0;st>>=1){ if (tid<st) red[tid]+=red[tid+st]; __syncthreads(); }
  if (tid==0){
    float M = decf(SC[0]);
    float se = ((const float*)SC)[1];
    out[0] = (float)L*(M + logf(se)) - red[0];
  }
  unsigned cnt = SC[2]; if (cnt>4096u) cnt=4096u;
  unsigned quota = SC[4];
  for (unsigned i=tid;i<cnt;i+=256u) lst[i]=EQL[i];
  __syncthreads();
  if (cnt <= quota){
    for (unsigned i=tid;i<cnt;i+=256u) out[1+lst[i]] = 1.0f;
  } else {
    for (unsigned i=tid;i<cnt;i+=256u){
      unsigned me=lst[i]; unsigned rank=0;
      for (unsigned j=0;j<cnt;++j) rank += (lst[j]<me)?1u:0u;
      if (rank<quota) out[1+me]=1.0f;   // stable tie-break: lowest index wins
    }
  }
}

extern "C" void kernel_launch(void* const* d_in, const int* in_sizes, int n_in,
                              void* d_out, int out_size, void* d_ws, size_t ws_size,
                              hipStream_t stream)
{
  const float* emb  = (const float*)d_in[0];
  const float* dtab = (const float*)d_in[1];
  const float* W    = (const float*)d_in[2];
  const int* dist   = (const int*)d_in[3];
  const int* labels = (const int*)d_in[4];
  const int* srcp   = (const int*)d_in[5];
  float* out = (float*)d_out;
  int N = in_sizes[3];
  int L = in_sizes[4];

  float* ws = (float*)d_ws;
  short* Wbs = (short*)ws;              // 4 quarters x 49152 shorts = 393216 B
  float* WD  = (float*)(Wbs + 196608);  // 768
  float* QN  = WD + 768;                // 1
  unsigned* SC = (unsigned*)(QN + 1);   // 8 scalars
  unsigned* H0 = SC + 8;                // 2048   } zero region starts here
  unsigned* H1 = H0 + 2048;             // 2048
  unsigned* H2 = H1 + 2048;             // 2048 (1024 used)
  float* Sg = (float*)(H2 + 2048);      // N  (doubles as Sv/logits)
  float* Qg = Sg + N;                   // N
  unsigned* UK = (unsigned*)(Qg + N);   // N
  unsigned* EQL = UK + N;               // 4096

  static bool lds_inited = false;
  if (!lds_inited){
    hipFuncSetAttribute((const void*)k2_main,
                        hipFuncAttributeMaxDynamicSharedMemorySize, 98304);
    lds_inited = true;
  }

  int grid  = (N + 255)/256;
  int grid1 = 257 + (6144 + 2*N + 255)/256;
  k1_setup<<<grid1,256,0,stream>>>(emb, dtab, W, srcp, Wbs, WD, QN, SC, H0, N);
  k2_main<<<256,512,98304,stream>>>(emb, dist, srcp, Wbs, WD, Sg, Qg, N);
  k2b_enc<<<grid,256,0,stream>>>(dist, Sg, Qg, QN, UK, SC, H0, N);
  ks_scan<<<1,256,0,stream>>>(H0, SC, 0);
  kh_hist<<<grid,256,0,stream>>>(UK, SC, H1, 1, N);
  ks_scan<<<1,256,0,stream>>>(H1, SC, 1);
  kh_hist<<<grid,256,0,stream>>>(UK, SC, H2, 2, N);
  ks_scan<<<1,256,0,stream>>>(H2, SC, 2);
  k6_final<<<grid,256,0,stream>>>(dist, srcp, Sg, UK, SC, EQL, out, N);
  k7_loss<<<1,256,0,stream>>>(labels, Sg, SC, EQL, out, L);
}